// Round 2
// baseline (153.737 us; speedup 1.0000x reference)
//
#include <hip/hip_runtime.h>
#include <hip/hip_bf16.h>

// RelationNetwork fused pipeline, bf16 MFMA (gfx950).
//
// Factorizations vs reference:
//  (1) pair@W1 = u[i]+v[j] with u=panel@W1[:F], v=panel@W1[F:] -> one
//      4096x512x512 GEMM instead of 147456x1024x256 (77 -> 2.15 GFLOP).
//  (2) 56 of 72 pairs are context-context (choice-invariant): their
//      sum_pairs relu(h1@W2+b2) is computed once per b (K2a), only the 16
//      choice-involving pairs run per (b,c) (K2b). 19.3 -> 6.2 GFLOP.
//
// ws layout (bytes):
//   [0,        524288)  Wp   bf16 [512][512]  Wp[j][k] = W1'[k][j] (B^T for K1)
//   [524288,   655360)  W2T  bf16 [256][256]  W2T[n][k] = W2[k][n]
//   [655360,   786432)  W3T  bf16 [256][256]
//   [786432,  9175040)  UV   f32  [4096][512] row b*16+p: p<8 ctx, p>=8 choice
//                                             cols 0..255 = u, 256..511 = v
//   [9175040, 9437184)  Sctx f32  [256][256]  per-b ctx-pair sum
//   [9437184,11534336)  agg  f32  [2048][256]

typedef __bf16 bf16_t;
typedef bf16_t bf16x8 __attribute__((ext_vector_type(8)));
typedef float f32x4 __attribute__((ext_vector_type(4)));

#define MFMA16(a, b, c) __builtin_amdgcn_mfma_f32_16x16x32_bf16((a), (b), (c), 0, 0, 0)

// ---- K0: weight transposes + bf16 conversion -------------------------------
__global__ __launch_bounds__(256) void prep_kernel(
    const float* __restrict__ W1, const float* __restrict__ W2,
    const float* __restrict__ W3, bf16_t* __restrict__ Wp,
    bf16_t* __restrict__ W2T, bf16_t* __restrict__ W3T) {
  const int idx = blockIdx.x * 256 + threadIdx.x;  // 1536*256 = 393216 exact
  if (idx < 262144) {                      // Wp[j][k], j<256: u-part, else v-part
    const int j = idx >> 9, k = idx & 511;
    const float v = (j < 256) ? W1[k * 256 + j] : W1[(512 + k) * 256 + (j - 256)];
    Wp[idx] = (bf16_t)v;
  } else if (idx < 327680) {               // W2T[n][k] = W2[k][n]
    const int s = idx - 262144;
    const int n = s >> 8, k = s & 255;
    W2T[s] = (bf16_t)W2[k * 256 + n];
  } else {                                 // W3T[n][k] = W3[k][n]
    const int s = idx - 327680;
    const int n = s >> 8, k = s & 255;
    W3T[s] = (bf16_t)W3[k * 256 + n];
  }
}

// ---- K1: UV = X @ W1'  (M=4096, N=512, K=512) ------------------------------
// grid 128 = 64 Mtiles(64 rows) x 2 Ntiles(256 cols).
// 4 waves/block; wave w covers n in [bn*256 + w*64, +64), 4mt x 4nt 16x16 tiles.
// (Round-1 bug: 8 Ntiles with a 256-wide per-block N-extent -> OOB + races.)
__global__ __launch_bounds__(256) void k1_kernel(
    const float* __restrict__ ctx, const float* __restrict__ cho,
    const bf16_t* __restrict__ Wp, float* __restrict__ UV) {
  const int bm = blockIdx.x & 63;
  const int bn = blockIdx.x >> 6;          // 0..1
  const int t = threadIdx.x;
  const int lane = t & 63;
  const int w = t >> 6;
  const int col = lane & 15;
  const int quad = lane >> 4;
  const float* aptr[4];
  for (int mt = 0; mt < 4; ++mt) {
    const int r = bm * 64 + mt * 16 + col;   // X row = b*16 + p
    const int bi = r >> 4;
    const int p = r & 15;
    aptr[mt] = (p < 8) ? ctx + (size_t)(bi * 8 + p) * 512
                       : cho + (size_t)(bi * 8 + (p - 8)) * 512;
  }
  f32x4 acc[4][4] = {};
  for (int ks = 0; ks < 16; ++ks) {
    const int k = ks * 32 + quad * 8;
    bf16x8 af[4], bf[4];
    for (int mt = 0; mt < 4; ++mt) {
      const f32x4 x0 = *(const f32x4*)(aptr[mt] + k);
      const f32x4 x1 = *(const f32x4*)(aptr[mt] + k + 4);
      for (int e = 0; e < 4; ++e) {
        af[mt][e] = (bf16_t)x0[e];
        af[mt][e + 4] = (bf16_t)x1[e];
      }
    }
    for (int nt = 0; nt < 4; ++nt) {
      const int n = bn * 256 + (w * 4 + nt) * 16 + col;
      bf[nt] = *(const bf16x8*)(Wp + (size_t)n * 512 + k);
    }
    for (int mt = 0; mt < 4; ++mt)
      for (int nt = 0; nt < 4; ++nt)
        acc[mt][nt] = MFMA16(af[mt], bf[nt], acc[mt][nt]);
  }
  for (int mt = 0; mt < 4; ++mt)
    for (int nt = 0; nt < 4; ++nt) {
      const int n = bn * 256 + (w * 4 + nt) * 16 + col;
      for (int reg = 0; reg < 4; ++reg) {
        const int r = bm * 64 + mt * 16 + quad * 4 + reg;
        UV[(size_t)r * 512 + n] = acc[mt][nt][reg];
      }
    }
}

// ---- K2a: per-b sum over 56 ctx-ctx pairs of relu(h1@W2+b2) ----------------
__global__ __launch_bounds__(256) void k2a_kernel(
    const float* __restrict__ UV, const float* __restrict__ b1,
    const float* __restrict__ b2, const bf16_t* __restrict__ W2T,
    float* __restrict__ Sctx) {
  __shared__ bf16_t h1[64][264];  // +8 pad: stride 132 dwords -> 2-way only
  const int b = blockIdx.x;
  const int t = threadIdx.x;
  {
    const int r = t >> 2;            // 0..63 (rows 56..63 zero pad)
    const int c0 = (t & 3) << 6;     // 4 threads/row, 64 cols each
    if (r < 56) {
      const int i = r / 7;
      const int jj = r - i * 7;
      const int j = jj + (jj >= i ? 1 : 0);
      const float* u = UV + (size_t)(b * 16 + i) * 512;
      const float* v = UV + (size_t)(b * 16 + j) * 512 + 256;
      for (int c = c0; c < c0 + 64; c += 4) {
        const f32x4 uu = *(const f32x4*)(u + c);
        const f32x4 vv = *(const f32x4*)(v + c);
        const f32x4 bb = *(const f32x4*)(b1 + c);
        for (int e = 0; e < 4; ++e)
          h1[r][c + e] = (bf16_t)fmaxf(uu[e] + vv[e] + bb[e], 0.0f);
      }
    } else {
      for (int c = c0; c < c0 + 64; ++c) h1[r][c] = (bf16_t)0.0f;
    }
  }
  __syncthreads();
  const int lane = t & 63;
  const int w = t >> 6;
  const int col = lane & 15;
  const int quad = lane >> 4;
  f32x4 acc[4][4] = {};
  for (int ks = 0; ks < 8; ++ks) {
    const int k = ks * 32 + quad * 8;
    bf16x8 af[4], bf[4];
    for (int mt = 0; mt < 4; ++mt)
      af[mt] = *(const bf16x8*)(&h1[mt * 16 + col][k]);
    for (int nt = 0; nt < 4; ++nt) {
      const int n = (w * 4 + nt) * 16 + col;
      bf[nt] = *(const bf16x8*)(W2T + n * 256 + k);
    }
    for (int mt = 0; mt < 4; ++mt)
      for (int nt = 0; nt < 4; ++nt)
        acc[mt][nt] = MFMA16(af[mt], bf[nt], acc[mt][nt]);
  }
  for (int nt = 0; nt < 4; ++nt) {
    const int n = (w * 4 + nt) * 16 + col;
    const float b2c = b2[n];
    float s = 0.0f;
    for (int mt = 0; mt < 4; ++mt)
      for (int reg = 0; reg < 4; ++reg) {
        const int row = mt * 16 + quad * 4 + reg;
        if (row < 56) s += fmaxf(acc[mt][nt][reg] + b2c, 0.0f);
      }
    s += __shfl_xor(s, 16);
    s += __shfl_xor(s, 32);
    if (lane < 16) Sctx[b * 256 + n] = s;
  }
}

// ---- K2b: 16 choice pairs x 4 choices/block; agg = (Sctx + Scho)/72 --------
__global__ __launch_bounds__(256) void k2b_kernel(
    const float* __restrict__ UV, const float* __restrict__ b1,
    const float* __restrict__ b2, const bf16_t* __restrict__ W2T,
    const float* __restrict__ Sctx, float* __restrict__ agg) {
  __shared__ bf16_t h1[64][264];
  const int b = blockIdx.x >> 1;
  const int cp = blockIdx.x & 1;  // choice half: cp*4 .. cp*4+3
  const int t = threadIdx.x;
  {
    const int r = t >> 2;                 // 0..63
    const int c0 = (t & 3) << 6;
    const int ch = cp * 4 + (r >> 4);     // choice 0..7
    const int rr = r & 15;                // pair row within this choice
    const float* u;
    const float* v;
    if (rr < 8) {  // (i=8(choice), j=rr)
      u = UV + (size_t)(b * 16 + 8 + ch) * 512;
      v = UV + (size_t)(b * 16 + rr) * 512 + 256;
    } else {       // (i=rr-8, j=8(choice))
      u = UV + (size_t)(b * 16 + (rr - 8)) * 512;
      v = UV + (size_t)(b * 16 + 8 + ch) * 512 + 256;
    }
    for (int c = c0; c < c0 + 64; c += 4) {
      const f32x4 uu = *(const f32x4*)(u + c);
      const f32x4 vv = *(const f32x4*)(v + c);
      const f32x4 bb = *(const f32x4*)(b1 + c);
      for (int e = 0; e < 4; ++e)
        h1[r][c + e] = (bf16_t)fmaxf(uu[e] + vv[e] + bb[e], 0.0f);
    }
  }
  __syncthreads();
  const int lane = t & 63;
  const int w = t >> 6;
  const int col = lane & 15;
  const int quad = lane >> 4;
  f32x4 acc[4][4] = {};
  for (int ks = 0; ks < 8; ++ks) {
    const int k = ks * 32 + quad * 8;
    bf16x8 af[4], bf[4];
    for (int mt = 0; mt < 4; ++mt)
      af[mt] = *(const bf16x8*)(&h1[mt * 16 + col][k]);
    for (int nt = 0; nt < 4; ++nt) {
      const int n = (w * 4 + nt) * 16 + col;
      bf[nt] = *(const bf16x8*)(W2T + n * 256 + k);
    }
    for (int mt = 0; mt < 4; ++mt)
      for (int nt = 0; nt < 4; ++nt)
        acc[mt][nt] = MFMA16(af[mt], bf[nt], acc[mt][nt]);
  }
  for (int nt = 0; nt < 4; ++nt) {
    const int n = (w * 4 + nt) * 16 + col;
    const float b2c = b2[n];
    const float sc = Sctx[b * 256 + n];
    for (int mt = 0; mt < 4; ++mt) {  // mt == choice group (16 rows each)
      float s = 0.0f;
      for (int reg = 0; reg < 4; ++reg)
        s += fmaxf(acc[mt][nt][reg] + b2c, 0.0f);
      s += __shfl_xor(s, 16);
      s += __shfl_xor(s, 32);
      if (lane < 16) {
        const int ch = cp * 4 + mt;
        agg[(size_t)(b * 8 + ch) * 256 + n] = (sc + s) * (1.0f / 72.0f);
      }
    }
  }
}

// ---- K3: score = relu(agg@W3+b3)@W4 + b4 -----------------------------------
// grid 32 blocks x 64 rows; MFMA for layer 3, shuffle-reduce dot for layer 4.
__global__ __launch_bounds__(256) void k3_kernel(
    const float* __restrict__ agg, const bf16_t* __restrict__ W3T,
    const float* __restrict__ b3, const float* __restrict__ W4,
    const float* __restrict__ b4, float* __restrict__ out) {
  __shared__ float red[4][64];
  const int blk = blockIdx.x;
  const int t = threadIdx.x;
  const int lane = t & 63;
  const int w = t >> 6;
  const int col = lane & 15;
  const int quad = lane >> 4;
  f32x4 acc[4][4] = {};
  for (int ks = 0; ks < 8; ++ks) {
    const int k = ks * 32 + quad * 8;
    bf16x8 af[4], bf[4];
    for (int mt = 0; mt < 4; ++mt) {
      const float* p = agg + (size_t)(blk * 64 + mt * 16 + col) * 256 + k;
      const f32x4 x0 = *(const f32x4*)p;
      const f32x4 x1 = *(const f32x4*)(p + 4);
      for (int e = 0; e < 4; ++e) {
        af[mt][e] = (bf16_t)x0[e];
        af[mt][e + 4] = (bf16_t)x1[e];
      }
    }
    for (int nt = 0; nt < 4; ++nt) {
      const int n = (w * 4 + nt) * 16 + col;
      bf[nt] = *(const bf16x8*)(W3T + n * 256 + k);
    }
    for (int mt = 0; mt < 4; ++mt)
      for (int nt = 0; nt < 4; ++nt)
        acc[mt][nt] = MFMA16(af[mt], bf[nt], acc[mt][nt]);
  }
  float pr[4][4];
  for (int mt = 0; mt < 4; ++mt)
    for (int reg = 0; reg < 4; ++reg) pr[mt][reg] = 0.0f;
  for (int nt = 0; nt < 4; ++nt) {
    const int n = (w * 4 + nt) * 16 + col;
    const float b3c = b3[n];
    const float w4c = W4[n];
    for (int mt = 0; mt < 4; ++mt)
      for (int reg = 0; reg < 4; ++reg)
        pr[mt][reg] += fmaxf(acc[mt][nt][reg] + b3c, 0.0f) * w4c;
  }
  for (int mt = 0; mt < 4; ++mt)
    for (int reg = 0; reg < 4; ++reg) {
      float s = pr[mt][reg];
      s += __shfl_xor(s, 1);
      s += __shfl_xor(s, 2);
      s += __shfl_xor(s, 4);
      s += __shfl_xor(s, 8);
      if (col == 0) red[w][mt * 16 + quad * 4 + reg] = s;
    }
  __syncthreads();
  if (t < 64) out[blk * 64 + t] = red[0][t] + red[1][t] + red[2][t] + red[3][t] + b4[0];
}

extern "C" void kernel_launch(void* const* d_in, const int* in_sizes, int n_in,
                              void* d_out, int out_size, void* d_ws, size_t ws_size,
                              hipStream_t stream) {
  (void)in_sizes; (void)n_in; (void)out_size; (void)ws_size;
  const float* ctx = (const float*)d_in[0];
  const float* cho = (const float*)d_in[1];
  const float* W1  = (const float*)d_in[2];
  const float* b1  = (const float*)d_in[3];
  const float* W2  = (const float*)d_in[4];
  const float* b2  = (const float*)d_in[5];
  const float* W3  = (const float*)d_in[6];
  const float* b3  = (const float*)d_in[7];
  const float* W4  = (const float*)d_in[8];
  const float* b4  = (const float*)d_in[9];
  char* ws = (char*)d_ws;
  bf16_t* Wp   = (bf16_t*)(ws + 0);
  bf16_t* W2T  = (bf16_t*)(ws + 524288);
  bf16_t* W3T  = (bf16_t*)(ws + 655360);
  float*  UV   = (float*)(ws + 786432);
  float*  Sctx = (float*)(ws + 9175040);
  float*  agg  = (float*)(ws + 9437184);
  float*  out  = (float*)d_out;

  prep_kernel<<<dim3(1536), dim3(256), 0, stream>>>(W1, W2, W3, Wp, W2T, W3T);
  k1_kernel<<<dim3(128), dim3(256), 0, stream>>>(ctx, cho, Wp, UV);
  k2a_kernel<<<dim3(256), dim3(256), 0, stream>>>(UV, b1, b2, W2T, Sctx);
  k2b_kernel<<<dim3(512), dim3(256), 0, stream>>>(UV, b1, b2, W2T, Sctx, agg);
  k3_kernel<<<dim3(32), dim3(256), 0, stream>>>(agg, W3T, b3, W4, b4, out);
}

// Round 3
// 130.444 us; speedup vs baseline: 1.1786x; 1.1786x over previous
//
#include <hip/hip_runtime.h>
#include <hip/hip_bf16.h>

// RelationNetwork fused pipeline, bf16 MFMA (gfx950).
//
// Factorizations:
//  (1) pair@W1 = u[i]+v[j]  -> one 4096x512x512 GEMM (K1).
//  (2) ctx-ctx pair sum is choice-invariant -> computed once per b inside the
//      merged K2 (kept in LDS, no global round-trip).
//
// ws layout (bytes):
//   [0,        524288)   Wp   bf16 [512][512]  Wp[j][k]=W1'[k][j]
//   [524288,   655360)   W2T  bf16 [256][256]
//   [655360,   786432)   W3T  bf16 [256][256]
//   [786432,   4980736)  Xb   bf16 [4096][512] row b*16+p (p<8 ctx, else choice)
//   [4980736, 13369344)  UV   f32  [4096][512] cols 0..255=u, 256..511=v
//   [13369344,14417920)  aggb bf16 [2048][256] row b*8+ch

typedef __bf16 bf16_t;
typedef bf16_t bf16x8 __attribute__((ext_vector_type(8)));
typedef bf16_t bf16x4 __attribute__((ext_vector_type(4)));
typedef float f32x4 __attribute__((ext_vector_type(4)));

#define MFMA16(a, b, c) __builtin_amdgcn_mfma_f32_16x16x32_bf16((a), (b), (c), 0, 0, 0)

// ---- K0: X->bf16 copy + weight transposes ----------------------------------
// blocks [0,2048): Xb (coalesced). blocks [2048,3584): Wp/W2T/W3T (as r2).
__global__ __launch_bounds__(256) void prep_kernel(
    const float* __restrict__ ctx, const float* __restrict__ cho,
    const float* __restrict__ W1, const float* __restrict__ W2,
    const float* __restrict__ W3, bf16_t* __restrict__ Xb,
    bf16_t* __restrict__ Wp, bf16_t* __restrict__ W2T,
    bf16_t* __restrict__ W3T) {
  const int blk = blockIdx.x;
  const int t = threadIdx.x;
  if (blk < 2048) {
    const int row = blk * 2 + (t >> 7);      // 0..4095 = b*16+p
    const int c4 = (t & 127) * 4;
    const int bi = row >> 4;
    const int p = row & 15;
    const float* src = (p < 8) ? ctx + (size_t)(bi * 8 + p) * 512 + c4
                               : cho + (size_t)(bi * 8 + (p - 8)) * 512 + c4;
    const f32x4 x = *(const f32x4*)src;
    bf16x4 y;
    for (int e = 0; e < 4; ++e) y[e] = (bf16_t)x[e];
    *(bf16x4*)(Xb + (size_t)row * 512 + c4) = y;
  } else {
    const int idx = (blk - 2048) * 256 + t;  // 0..393215
    if (idx < 262144) {                      // Wp[j][k]
      const int j = idx >> 9, k = idx & 511;
      const float v = (j < 256) ? W1[k * 256 + j] : W1[(512 + k) * 256 + (j - 256)];
      Wp[idx] = (bf16_t)v;
    } else if (idx < 327680) {               // W2T[n][k] = W2[k][n]
      const int s = idx - 262144;
      const int n = s >> 8, k = s & 255;
      W2T[s] = (bf16_t)W2[k * 256 + n];
    } else {                                 // W3T[n][k] = W3[k][n]
      const int s = idx - 327680;
      const int n = s >> 8, k = s & 255;
      W3T[s] = (bf16_t)W3[k * 256 + n];
    }
  }
}

// ---- K1: UV = Xb @ Wp^T  (M=4096, N=512, K=512) ----------------------------
// 256 blocks = 64 Mtiles(64) x 4 Ntiles(128); 4 waves, wave = 4mt x 2nt.
__global__ __launch_bounds__(256) void k1_kernel(
    const bf16_t* __restrict__ Xb, const bf16_t* __restrict__ Wp,
    float* __restrict__ UV) {
  const int bm = blockIdx.x & 63;
  const int bn = blockIdx.x >> 6;          // 0..3
  const int t = threadIdx.x;
  const int lane = t & 63;
  const int w = t >> 6;
  const int col = lane & 15;
  const int quad = lane >> 4;
  f32x4 acc[4][2] = {};
  for (int ks = 0; ks < 16; ++ks) {
    const int k = ks * 32 + quad * 8;
    bf16x8 af[4], bf[2];
    for (int mt = 0; mt < 4; ++mt) {
      const int r = bm * 64 + mt * 16 + col;
      af[mt] = *(const bf16x8*)(Xb + (size_t)r * 512 + k);
    }
    for (int nt = 0; nt < 2; ++nt) {
      const int n = bn * 128 + (w * 2 + nt) * 16 + col;
      bf[nt] = *(const bf16x8*)(Wp + (size_t)n * 512 + k);
    }
    for (int mt = 0; mt < 4; ++mt)
      for (int nt = 0; nt < 2; ++nt)
        acc[mt][nt] = MFMA16(af[mt], bf[nt], acc[mt][nt]);
  }
  for (int mt = 0; mt < 4; ++mt)
    for (int nt = 0; nt < 2; ++nt) {
      const int n = bn * 128 + (w * 2 + nt) * 16 + col;
      for (int reg = 0; reg < 4; ++reg) {
        const int r = bm * 64 + mt * 16 + quad * 4 + reg;
        UV[(size_t)r * 512 + n] = acc[mt][nt][reg];
      }
    }
}

// ---- K2: merged relation stage. One block per b (256 blocks, 512 thr). -----
// Rows r in [0,192): r<56 ctx pair; 56..63 zero pad; r=64+ch*16+rr choice pair.
// h1 staged in LDS in two K=128 phases (52 KB). 8 waves: w&1 -> mt half (6),
// w>>1 -> nt quarter (4). Epilogue: per-tile column sums -> S[9][256] in LDS,
// aggb[b*8+ch][n] = bf16((Sctx + Scho[ch])/72).
__global__ __launch_bounds__(512) void k2_kernel(
    const float* __restrict__ UV, const float* __restrict__ b1,
    const float* __restrict__ b2, const bf16_t* __restrict__ W2T,
    bf16_t* __restrict__ aggb) {
  __shared__ bf16_t h1[192][136];  // K=128 phase + 8 pad (uniform bank spread)
  __shared__ float S[9][256];      // 0: ctx sum; 1+ch: choice sums
  const int b = blockIdx.x;
  const int t = threadIdx.x;
  const int lane = t & 63;
  const int w = t >> 6;
  const int col = lane & 15;
  const int quad = lane >> 4;
  // staging role (threads 0..383: 2 per row)
  const float* su = nullptr;
  const float* sv = nullptr;
  int sr = 0, sc0 = 0;
  if (t < 384) {
    sr = t >> 1;
    sc0 = (t & 1) * 64;
    if (sr < 56) {
      const int i = sr / 7;
      const int jj = sr - i * 7;
      const int j = jj + (jj >= i ? 1 : 0);
      su = UV + (size_t)(b * 16 + i) * 512;
      sv = UV + (size_t)(b * 16 + j) * 512 + 256;
    } else if (sr >= 64) {
      const int ch = (sr - 64) >> 4;
      const int rr = (sr - 64) & 15;
      if (rr < 8) {
        su = UV + (size_t)(b * 16 + 8 + ch) * 512;
        sv = UV + (size_t)(b * 16 + rr) * 512 + 256;
      } else {
        su = UV + (size_t)(b * 16 + (rr - 8)) * 512;
        sv = UV + (size_t)(b * 16 + 8 + ch) * 512 + 256;
      }
    }
  }
  const int mtb = (w & 1) * 6;   // mt base (6 tiles)
  const int q = w >> 1;          // nt quarter
  f32x4 acc[6][4] = {};
  for (int half = 0; half < 2; ++half) {
    const int kbase = half * 128;
    if (t < 384) {
      if (su) {
        for (int c = sc0; c < sc0 + 64; c += 4) {
          const f32x4 uu = *(const f32x4*)(su + kbase + c);
          const f32x4 vv = *(const f32x4*)(sv + kbase + c);
          const f32x4 bb = *(const f32x4*)(b1 + kbase + c);
          bf16x4 y;
          for (int e = 0; e < 4; ++e) y[e] = (bf16_t)fmaxf(uu[e] + vv[e] + bb[e], 0.0f);
          *(bf16x4*)(&h1[sr][c]) = y;
        }
      } else {
        for (int c = sc0; c < sc0 + 64; c += 4)
          *(bf16x4*)(&h1[sr][c]) = (bf16x4)0.0f;
      }
    }
    __syncthreads();
    for (int ks = 0; ks < 4; ++ks) {
      const int k = ks * 32 + quad * 8;  // within-phase k, <128
      bf16x8 af[6], bf[4];
      for (int mt = 0; mt < 6; ++mt)
        af[mt] = *(const bf16x8*)(&h1[(mtb + mt) * 16 + col][k]);
      for (int nt = 0; nt < 4; ++nt) {
        const int n = q * 64 + nt * 16 + col;
        bf[nt] = *(const bf16x8*)(W2T + (size_t)n * 256 + kbase + k);
      }
      for (int mt = 0; mt < 6; ++mt)
        for (int nt = 0; nt < 4; ++nt)
          acc[mt][nt] = MFMA16(af[mt], bf[nt], acc[mt][nt]);
    }
    __syncthreads();
  }
  // epilogue: tile-column sums of relu(acc + b2)
  for (int nt = 0; nt < 4; ++nt) {
    const int n = q * 64 + nt * 16 + col;
    const float b2c = b2[n];
    float sctx = 0.0f;
    for (int mt = 0; mt < 6; ++mt) {
      const int gm = mtb + mt;
      float s = 0.0f;
      for (int reg = 0; reg < 4; ++reg) {
        const int row = gm * 16 + quad * 4 + reg;
        if (row < 56 || row >= 64) s += fmaxf(acc[mt][nt][reg] + b2c, 0.0f);
      }
      s += __shfl_xor(s, 16);
      s += __shfl_xor(s, 32);
      if (gm < 4) {
        sctx += s;                       // only waves with mtb==0
      } else if (lane < 16) {
        S[1 + (gm - 4)][n] = s;
      }
    }
    if (mtb == 0 && lane < 16) S[0][n] = sctx;
  }
  __syncthreads();
  // write aggb: 512 threads = 8 ch x 64 lanes x 4 cols
  {
    const int ch = t >> 6;
    const int n0 = (t & 63) * 4;
    bf16x4 y;
    for (int e = 0; e < 4; ++e)
      y[e] = (bf16_t)((S[0][n0 + e] + S[1 + ch][n0 + e]) * (1.0f / 72.0f));
    *(bf16x4*)(aggb + (size_t)(b * 8 + ch) * 256 + n0) = y;
  }
}

// ---- K3: score = relu(aggb@W3+b3)@W4 + b4 ----------------------------------
__global__ __launch_bounds__(256) void k3_kernel(
    const bf16_t* __restrict__ aggb, const bf16_t* __restrict__ W3T,
    const float* __restrict__ b3, const float* __restrict__ W4,
    const float* __restrict__ b4, float* __restrict__ out) {
  __shared__ float red[4][64];
  const int blk = blockIdx.x;
  const int t = threadIdx.x;
  const int lane = t & 63;
  const int w = t >> 6;
  const int col = lane & 15;
  const int quad = lane >> 4;
  f32x4 acc[4][4] = {};
  for (int ks = 0; ks < 8; ++ks) {
    const int k = ks * 32 + quad * 8;
    bf16x8 af[4], bf[4];
    for (int mt = 0; mt < 4; ++mt)
      af[mt] = *(const bf16x8*)(aggb + (size_t)(blk * 64 + mt * 16 + col) * 256 + k);
    for (int nt = 0; nt < 4; ++nt) {
      const int n = (w * 4 + nt) * 16 + col;
      bf[nt] = *(const bf16x8*)(W3T + (size_t)n * 256 + k);
    }
    for (int mt = 0; mt < 4; ++mt)
      for (int nt = 0; nt < 4; ++nt)
        acc[mt][nt] = MFMA16(af[mt], bf[nt], acc[mt][nt]);
  }
  float pr[4][4];
  for (int mt = 0; mt < 4; ++mt)
    for (int reg = 0; reg < 4; ++reg) pr[mt][reg] = 0.0f;
  for (int nt = 0; nt < 4; ++nt) {
    const int n = (w * 4 + nt) * 16 + col;
    const float b3c = b3[n];
    const float w4c = W4[n];
    for (int mt = 0; mt < 4; ++mt)
      for (int reg = 0; reg < 4; ++reg)
        pr[mt][reg] += fmaxf(acc[mt][nt][reg] + b3c, 0.0f) * w4c;
  }
  for (int mt = 0; mt < 4; ++mt)
    for (int reg = 0; reg < 4; ++reg) {
      float s = pr[mt][reg];
      s += __shfl_xor(s, 1);
      s += __shfl_xor(s, 2);
      s += __shfl_xor(s, 4);
      s += __shfl_xor(s, 8);
      if (col == 0) red[w][mt * 16 + quad * 4 + reg] = s;
    }
  __syncthreads();
  if (t < 64) out[blk * 64 + t] = red[0][t] + red[1][t] + red[2][t] + red[3][t] + b4[0];
}

extern "C" void kernel_launch(void* const* d_in, const int* in_sizes, int n_in,
                              void* d_out, int out_size, void* d_ws, size_t ws_size,
                              hipStream_t stream) {
  (void)in_sizes; (void)n_in; (void)out_size; (void)ws_size;
  const float* ctx = (const float*)d_in[0];
  const float* cho = (const float*)d_in[1];
  const float* W1  = (const float*)d_in[2];
  const float* b1  = (const float*)d_in[3];
  const float* W2  = (const float*)d_in[4];
  const float* b2  = (const float*)d_in[5];
  const float* W3  = (const float*)d_in[6];
  const float* b3  = (const float*)d_in[7];
  const float* W4  = (const float*)d_in[8];
  const float* b4  = (const float*)d_in[9];
  char* ws = (char*)d_ws;
  bf16_t* Wp   = (bf16_t*)(ws + 0);
  bf16_t* W2T  = (bf16_t*)(ws + 524288);
  bf16_t* W3T  = (bf16_t*)(ws + 655360);
  bf16_t* Xb   = (bf16_t*)(ws + 786432);
  float*  UV   = (float*)(ws + 4980736);
  bf16_t* aggb = (bf16_t*)(ws + 13369344);
  float*  out  = (float*)d_out;

  prep_kernel<<<dim3(3584), dim3(256), 0, stream>>>(ctx, cho, W1, W2, W3, Xb, Wp, W2T, W3T);
  k1_kernel<<<dim3(256), dim3(256), 0, stream>>>(Xb, Wp, UV);
  k2_kernel<<<dim3(256), dim3(512), 0, stream>>>(UV, b1, b2, W2T, aggb);
  k3_kernel<<<dim3(32), dim3(256), 0, stream>>>(aggb, W3T, b3, W4, b4, out);
}

// Round 4
// 129.491 us; speedup vs baseline: 1.1872x; 1.0074x over previous
//
#include <hip/hip_runtime.h>
#include <hip/hip_bf16.h>

// RelationNetwork fused pipeline, bf16 MFMA (gfx950).
//
// Factorizations:
//  (1) pair@W1 = u[i]+v[j]  -> one 4096x512x512 GEMM (K1).
//  (2) ctx-ctx pair sum is choice-invariant -> computed once per b inside K2.
//  (3) f_phi fused into K2: block b owns agg rows [b*8,b*8+8) in LDS, runs the
//      8x256 @ 256x256 MLP + W4 dot in-block -> no K3 kernel, no aggb RT.
//
// ws layout (bytes):
//   [0,        524288)   Wp   bf16 [512][512]  Wp[j][k]=W1'[k][j]
//   [524288,   655360)   W2T  bf16 [256][256]
//   [655360,   786432)   W3T  bf16 [256][256]
//   [786432,   4980736)  Xb   bf16 [4096][512] row b*16+p (p<8 ctx, else choice)
//   [4980736, 13369344)  UV   f32  [4096][512] cols 0..255=u, 256..511=v

typedef __bf16 bf16_t;
typedef bf16_t bf16x8 __attribute__((ext_vector_type(8)));
typedef bf16_t bf16x4 __attribute__((ext_vector_type(4)));
typedef float f32x4 __attribute__((ext_vector_type(4)));

#define MFMA16(a, b, c) __builtin_amdgcn_mfma_f32_16x16x32_bf16((a), (b), (c), 0, 0, 0)

// ---- K0: X->bf16 copy + weight transposes ----------------------------------
__global__ __launch_bounds__(256) void prep_kernel(
    const float* __restrict__ ctx, const float* __restrict__ cho,
    const float* __restrict__ W1, const float* __restrict__ W2,
    const float* __restrict__ W3, bf16_t* __restrict__ Xb,
    bf16_t* __restrict__ Wp, bf16_t* __restrict__ W2T,
    bf16_t* __restrict__ W3T) {
  const int blk = blockIdx.x;
  const int t = threadIdx.x;
  if (blk < 2048) {
    const int row = blk * 2 + (t >> 7);      // 0..4095 = b*16+p
    const int c4 = (t & 127) * 4;
    const int bi = row >> 4;
    const int p = row & 15;
    const float* src = (p < 8) ? ctx + (size_t)(bi * 8 + p) * 512 + c4
                               : cho + (size_t)(bi * 8 + (p - 8)) * 512 + c4;
    const f32x4 x = *(const f32x4*)src;
    bf16x4 y;
    for (int e = 0; e < 4; ++e) y[e] = (bf16_t)x[e];
    *(bf16x4*)(Xb + (size_t)row * 512 + c4) = y;
  } else {
    const int idx = (blk - 2048) * 256 + t;  // 0..393215
    if (idx < 262144) {                      // Wp[j][k]
      const int j = idx >> 9, k = idx & 511;
      const float v = (j < 256) ? W1[k * 256 + j] : W1[(512 + k) * 256 + (j - 256)];
      Wp[idx] = (bf16_t)v;
    } else if (idx < 327680) {               // W2T[n][k] = W2[k][n]
      const int s = idx - 262144;
      const int n = s >> 8, k = s & 255;
      W2T[s] = (bf16_t)W2[k * 256 + n];
    } else {                                 // W3T[n][k] = W3[k][n]
      const int s = idx - 327680;
      const int n = s >> 8, k = s & 255;
      W3T[s] = (bf16_t)W3[k * 256 + n];
    }
  }
}

// ---- K1: UV = Xb @ Wp^T  (M=4096, N=512, K=512) ----------------------------
// 512 blocks = 64 Mtiles(64) x 8 Ntiles(64); 2 blocks/CU for latency overlap.
// 4 waves/block; wave w covers n in [bn*64 + w*16, +16), 4mt x 1nt.
__global__ __launch_bounds__(256) void k1_kernel(
    const bf16_t* __restrict__ Xb, const bf16_t* __restrict__ Wp,
    float* __restrict__ UV) {
  const int bm = blockIdx.x & 63;
  const int bn = blockIdx.x >> 6;          // 0..7
  const int t = threadIdx.x;
  const int lane = t & 63;
  const int w = t >> 6;
  const int col = lane & 15;
  const int quad = lane >> 4;
  const int n = bn * 64 + w * 16 + col;
  f32x4 acc[4] = {};
  for (int ks = 0; ks < 16; ++ks) {
    const int k = ks * 32 + quad * 8;
    bf16x8 af[4];
    for (int mt = 0; mt < 4; ++mt) {
      const int r = bm * 64 + mt * 16 + col;
      af[mt] = *(const bf16x8*)(Xb + (size_t)r * 512 + k);
    }
    const bf16x8 bf = *(const bf16x8*)(Wp + (size_t)n * 512 + k);
    for (int mt = 0; mt < 4; ++mt) acc[mt] = MFMA16(af[mt], bf, acc[mt]);
  }
  for (int mt = 0; mt < 4; ++mt)
    for (int reg = 0; reg < 4; ++reg) {
      const int r = bm * 64 + mt * 16 + quad * 4 + reg;
      UV[(size_t)r * 512 + n] = acc[mt][reg];
    }
}

// ---- K2: merged relation stage + f_phi. One block per b (256 blk, 512 thr).
// Rows r in [0,192): r<56 ctx pair; 56..63 zero pad; r=64+ch*16+rr choice pair.
// h1 staged in LDS in two K=128 phases (52 KB). 8 waves: w&1 -> mt half (6),
// w>>1 -> nt quarter. Then (LDS overlay, h1 dead): S[9][256] column sums ->
// Ag[16][264] bf16 agg rows -> f_phi MFMA vs W3T -> W4 dot -> out[b*8+ch].
__global__ __launch_bounds__(512) void k2_kernel(
    const float* __restrict__ UV, const float* __restrict__ b1,
    const float* __restrict__ b2, const bf16_t* __restrict__ W2T,
    const bf16_t* __restrict__ W3T, const float* __restrict__ b3,
    const float* __restrict__ W4, const float* __restrict__ b4,
    float* __restrict__ out) {
  __shared__ char smem[52224];                      // h1[192][136] bf16
  bf16_t (*h1)[136] = (bf16_t(*)[136])smem;
  float (*S)[256] = (float(*)[256])smem;            // 9216 B (after h1 dead)
  bf16_t (*Ag)[264] = (bf16_t(*)[264])(smem + 9216);   // 8448 B
  float (*red)[8] = (float(*)[8])(smem + 9216 + 8448); // 256 B
  const int b = blockIdx.x;
  const int t = threadIdx.x;
  const int lane = t & 63;
  const int w = t >> 6;
  const int col = lane & 15;
  const int quad = lane >> 4;
  // staging role (threads 0..383: 2 per row)
  const float* su = nullptr;
  const float* sv = nullptr;
  int sr = 0, sc0 = 0;
  if (t < 384) {
    sr = t >> 1;
    sc0 = (t & 1) * 64;
    if (sr < 56) {
      const int i = sr / 7;
      const int jj = sr - i * 7;
      const int j = jj + (jj >= i ? 1 : 0);
      su = UV + (size_t)(b * 16 + i) * 512;
      sv = UV + (size_t)(b * 16 + j) * 512 + 256;
    } else if (sr >= 64) {
      const int ch = (sr - 64) >> 4;
      const int rr = (sr - 64) & 15;
      if (rr < 8) {
        su = UV + (size_t)(b * 16 + 8 + ch) * 512;
        sv = UV + (size_t)(b * 16 + rr) * 512 + 256;
      } else {
        su = UV + (size_t)(b * 16 + (rr - 8)) * 512;
        sv = UV + (size_t)(b * 16 + 8 + ch) * 512 + 256;
      }
    }
  }
  const int mtb = (w & 1) * 6;   // mt base (6 tiles)
  const int q = w >> 1;          // nt quarter
  f32x4 acc[6][4] = {};
  for (int half = 0; half < 2; ++half) {
    const int kbase = half * 128;
    if (t < 384) {
      if (su) {
        for (int c = sc0; c < sc0 + 64; c += 4) {
          const f32x4 uu = *(const f32x4*)(su + kbase + c);
          const f32x4 vv = *(const f32x4*)(sv + kbase + c);
          const f32x4 bb = *(const f32x4*)(b1 + kbase + c);
          bf16x4 y;
          for (int e = 0; e < 4; ++e) y[e] = (bf16_t)fmaxf(uu[e] + vv[e] + bb[e], 0.0f);
          *(bf16x4*)(&h1[sr][c]) = y;
        }
      } else {
        for (int c = sc0; c < sc0 + 64; c += 4)
          *(bf16x4*)(&h1[sr][c]) = (bf16x4)0.0f;
      }
    }
    __syncthreads();
    for (int ks = 0; ks < 4; ++ks) {
      const int k = ks * 32 + quad * 8;  // within-phase k, <128
      bf16x8 af[6], bf[4];
      for (int mt = 0; mt < 6; ++mt)
        af[mt] = *(const bf16x8*)(&h1[(mtb + mt) * 16 + col][k]);
      for (int nt = 0; nt < 4; ++nt) {
        const int n = q * 64 + nt * 16 + col;
        bf[nt] = *(const bf16x8*)(W2T + (size_t)n * 256 + kbase + k);
      }
      for (int mt = 0; mt < 6; ++mt)
        for (int nt = 0; nt < 4; ++nt)
          acc[mt][nt] = MFMA16(af[mt], bf[nt], acc[mt][nt]);
    }
    __syncthreads();   // MFMAs done; h1 dead after half==1 -> S/Ag may overlay
  }
  // epilogue: tile-column sums of relu(acc + b2) -> S (overlays h1)
  for (int nt = 0; nt < 4; ++nt) {
    const int n = q * 64 + nt * 16 + col;
    const float b2c = b2[n];
    float sctx = 0.0f;
    for (int mt = 0; mt < 6; ++mt) {
      const int gm = mtb + mt;
      float s = 0.0f;
      for (int reg = 0; reg < 4; ++reg) {
        const int row = gm * 16 + quad * 4 + reg;
        if (row < 56 || row >= 64) s += fmaxf(acc[mt][nt][reg] + b2c, 0.0f);
      }
      s += __shfl_xor(s, 16);
      s += __shfl_xor(s, 32);
      if (gm < 4) {
        sctx += s;                       // only waves with mtb==0
      } else if (lane < 16) {
        S[1 + (gm - 4)][n] = s;
      }
    }
    if (mtb == 0 && lane < 16) S[0][n] = sctx;
  }
  __syncthreads();
  // Ag rows 0..7 = bf16 agg for each choice; rows 8..15 zero (M=16 pad)
  {
    const int ch = t >> 6;
    const int n0 = (t & 63) * 4;
    bf16x4 y;
    for (int e = 0; e < 4; ++e)
      y[e] = (bf16_t)((S[0][n0 + e] + S[1 + ch][n0 + e]) * (1.0f / 72.0f));
    *(bf16x4*)(&Ag[ch][n0]) = y;
    *(bf16x4*)(&Ag[8 + ch][n0]) = (bf16x4)0.0f;
  }
  __syncthreads();
  // f_phi: g = relu(Ag@W3+b3); score = g@W4 + b4. wave w -> n in [w*32,+32).
  f32x4 acc2[2] = {};
  for (int ks = 0; ks < 8; ++ks) {
    const int k = ks * 32 + quad * 8;
    const bf16x8 af = *(const bf16x8*)(&Ag[col][k]);
    for (int nt = 0; nt < 2; ++nt) {
      const int n = w * 32 + nt * 16 + col;
      const bf16x8 bf = *(const bf16x8*)(W3T + (size_t)n * 256 + k);
      acc2[nt] = MFMA16(af, bf, acc2[nt]);
    }
  }
  for (int reg = 0; reg < 4; ++reg) {
    float pr = 0.0f;
    for (int nt = 0; nt < 2; ++nt) {
      const int n = w * 32 + nt * 16 + col;
      pr += fmaxf(acc2[nt][reg] + b3[n], 0.0f) * W4[n];
    }
    pr += __shfl_xor(pr, 1);
    pr += __shfl_xor(pr, 2);
    pr += __shfl_xor(pr, 4);
    pr += __shfl_xor(pr, 8);
    if (col == 0 && quad < 2) red[w][quad * 4 + reg] = pr;  // rows 8..15 dropped
  }
  __syncthreads();
  if (t < 8) {
    float sc = b4[0];
    for (int ww = 0; ww < 8; ++ww) sc += red[ww][t];
    out[b * 8 + t] = sc;
  }
}

extern "C" void kernel_launch(void* const* d_in, const int* in_sizes, int n_in,
                              void* d_out, int out_size, void* d_ws, size_t ws_size,
                              hipStream_t stream) {
  (void)in_sizes; (void)n_in; (void)out_size; (void)ws_size;
  const float* ctx = (const float*)d_in[0];
  const float* cho = (const float*)d_in[1];
  const float* W1  = (const float*)d_in[2];
  const float* b1  = (const float*)d_in[3];
  const float* W2  = (const float*)d_in[4];
  const float* b2  = (const float*)d_in[5];
  const float* W3  = (const float*)d_in[6];
  const float* b3  = (const float*)d_in[7];
  const float* W4  = (const float*)d_in[8];
  const float* b4  = (const float*)d_in[9];
  char* ws = (char*)d_ws;
  bf16_t* Wp   = (bf16_t*)(ws + 0);
  bf16_t* W2T  = (bf16_t*)(ws + 524288);
  bf16_t* W3T  = (bf16_t*)(ws + 655360);
  bf16_t* Xb   = (bf16_t*)(ws + 786432);
  float*  UV   = (float*)(ws + 4980736);
  float*  out  = (float*)d_out;

  prep_kernel<<<dim3(3584), dim3(256), 0, stream>>>(ctx, cho, W1, W2, W3, Xb, Wp, W2T, W3T);
  k1_kernel<<<dim3(512), dim3(256), 0, stream>>>(Xb, Wp, UV);
  k2_kernel<<<dim3(256), dim3(512), 0, stream>>>(UV, b1, b2, W2T, W3T, b3, W4, b4, out);
}

// Round 5
// 115.652 us; speedup vs baseline: 1.3293x; 1.1197x over previous
//
#include <hip/hip_runtime.h>
#include <hip/hip_bf16.h>

// RelationNetwork fused pipeline, bf16 MFMA (gfx950).
//
// Factorizations:
//  (1) pair@W1 = u[i]+v[j]  -> one 4096x512x512 GEMM (K1).
//  (2) ctx-ctx pair sum is choice-invariant -> computed once per b inside K2.
//  (3) f_phi fused into K2 (agg rows live in LDS; no K3, no aggb round-trip).
//  (4) r5: no Xb staging pass -- K1 converts fp32 X into a shared LDS A-tile
//      once per block (4 waves reuse it), prep handles weights only.
//
// ws layout (bytes):
//   [0,        524288)   Wp   bf16 [512][512]  Wp[j][k]=W1'[k][j]
//   [524288,   655360)   W2T  bf16 [256][256]
//   [655360,   786432)   W3T  bf16 [256][256]
//   [786432,   9175040)  UV   f32  [4096][512] row b*16+p; cols 0..255=u, 256..511=v

typedef __bf16 bf16_t;
typedef bf16_t bf16x8 __attribute__((ext_vector_type(8)));
typedef bf16_t bf16x4 __attribute__((ext_vector_type(4)));
typedef float f32x4 __attribute__((ext_vector_type(4)));

#define MFMA16(a, b, c) __builtin_amdgcn_mfma_f32_16x16x32_bf16((a), (b), (c), 0, 0, 0)

// ---- K0: weight transposes + bf16 conversion (1536 blocks) -----------------
__global__ __launch_bounds__(256) void prep_kernel(
    const float* __restrict__ W1, const float* __restrict__ W2,
    const float* __restrict__ W3, bf16_t* __restrict__ Wp,
    bf16_t* __restrict__ W2T, bf16_t* __restrict__ W3T) {
  const int idx = blockIdx.x * 256 + threadIdx.x;  // 0..393215
  if (idx < 262144) {                      // Wp[j][k], j<256: u-part, else v-part
    const int j = idx >> 9, k = idx & 511;
    const float v = (j < 256) ? W1[k * 256 + j] : W1[(512 + k) * 256 + (j - 256)];
    Wp[idx] = (bf16_t)v;
  } else if (idx < 327680) {               // W2T[n][k] = W2[k][n]
    const int s = idx - 262144;
    const int n = s >> 8, k = s & 255;
    W2T[s] = (bf16_t)W2[k * 256 + n];
  } else {                                 // W3T[n][k] = W3[k][n]
    const int s = idx - 327680;
    const int n = s >> 8, k = s & 255;
    W3T[s] = (bf16_t)W3[k * 256 + n];
  }
}

// ---- K1: UV = X @ Wp^T  (M=4096, N=512, K=512) -----------------------------
// 512 blocks = 64 Mtiles(64) x 8 Ntiles(64); 2 blocks/CU.
// A-tile staged fp32->bf16 into LDS once per block (shared by all 4 waves),
// two K=256 halves. Staging: 4 threads/row, 16B-interleaved columns so global
// loads coalesce 64B/group and LDS write banks spread (4r+{0,2,4,6}).
__global__ __launch_bounds__(256) void k1_kernel(
    const float* __restrict__ ctx, const float* __restrict__ cho,
    const bf16_t* __restrict__ Wp, float* __restrict__ UV) {
  __shared__ bf16_t As[64][264];           // 33.8 KB; row bank-stride 4 -> 2-way max
  const int bm = blockIdx.x & 63;
  const int bn = blockIdx.x >> 6;          // 0..7
  const int t = threadIdx.x;
  const int lane = t & 63;
  const int w = t >> 6;
  const int col = lane & 15;
  const int quad = lane >> 4;
  const int n = bn * 64 + w * 16 + col;
  // staging role: row sr, column base cb (16B-interleaved)
  const int sr = t >> 2;                   // 0..63
  const int gr = bm * 64 + sr;             // X row = b*16 + p
  const int bi = gr >> 4;
  const int p = gr & 15;
  const float* src = (p < 8) ? ctx + (size_t)(bi * 8 + p) * 512
                             : cho + (size_t)(bi * 8 + (p - 8)) * 512;
  const int cb = (t & 3) * 4;
  f32x4 acc[4] = {};
  for (int half = 0; half < 2; ++half) {
    const int kbase = half * 256;
    for (int i = 0; i < 16; ++i) {
      const int c = cb + i * 16;
      const f32x4 x = *(const f32x4*)(src + kbase + c);
      bf16x4 y;
      for (int e = 0; e < 4; ++e) y[e] = (bf16_t)x[e];
      *(bf16x4*)(&As[sr][c]) = y;
    }
    __syncthreads();
    for (int ks = 0; ks < 8; ++ks) {
      const int k = ks * 32 + quad * 8;
      bf16x8 af[4];
      for (int mt = 0; mt < 4; ++mt)
        af[mt] = *(const bf16x8*)(&As[mt * 16 + col][k]);
      const bf16x8 bf = *(const bf16x8*)(Wp + (size_t)n * 512 + kbase + k);
      for (int mt = 0; mt < 4; ++mt) acc[mt] = MFMA16(af[mt], bf, acc[mt]);
    }
    __syncthreads();
  }
  for (int mt = 0; mt < 4; ++mt)
    for (int reg = 0; reg < 4; ++reg) {
      const int r = bm * 64 + mt * 16 + quad * 4 + reg;
      UV[(size_t)r * 512 + n] = acc[mt][reg];
    }
}

// ---- K2: merged relation stage + f_phi. One block per b (256 blk, 512 thr).
// Rows r in [0,192): r<56 ctx pair; 56..63 zero pad; r=64+ch*16+rr choice pair.
// h1 staged in LDS in two K=128 phases (52 KB). 8 waves: w&1 -> mt half (6),
// w>>1 -> nt quarter. Then (LDS overlay, h1 dead): S[9][256] column sums ->
// Ag[16][264] bf16 agg rows -> f_phi MFMA vs W3T -> W4 dot -> out[b*8+ch].
__global__ __launch_bounds__(512) void k2_kernel(
    const float* __restrict__ UV, const float* __restrict__ b1,
    const float* __restrict__ b2, const bf16_t* __restrict__ W2T,
    const bf16_t* __restrict__ W3T, const float* __restrict__ b3,
    const float* __restrict__ W4, const float* __restrict__ b4,
    float* __restrict__ out) {
  __shared__ char smem[52224];                      // h1[192][136] bf16
  bf16_t (*h1)[136] = (bf16_t(*)[136])smem;
  float (*S)[256] = (float(*)[256])smem;            // 9216 B (after h1 dead)
  bf16_t (*Ag)[264] = (bf16_t(*)[264])(smem + 9216);   // 8448 B
  float (*red)[8] = (float(*)[8])(smem + 9216 + 8448); // 256 B
  const int b = blockIdx.x;
  const int t = threadIdx.x;
  const int lane = t & 63;
  const int w = t >> 6;
  const int col = lane & 15;
  const int quad = lane >> 4;
  // staging role (threads 0..383: 2 per row)
  const float* su = nullptr;
  const float* sv = nullptr;
  int sr = 0, sc0 = 0;
  if (t < 384) {
    sr = t >> 1;
    sc0 = (t & 1) * 64;
    if (sr < 56) {
      const int i = sr / 7;
      const int jj = sr - i * 7;
      const int j = jj + (jj >= i ? 1 : 0);
      su = UV + (size_t)(b * 16 + i) * 512;
      sv = UV + (size_t)(b * 16 + j) * 512 + 256;
    } else if (sr >= 64) {
      const int ch = (sr - 64) >> 4;
      const int rr = (sr - 64) & 15;
      if (rr < 8) {
        su = UV + (size_t)(b * 16 + 8 + ch) * 512;
        sv = UV + (size_t)(b * 16 + rr) * 512 + 256;
      } else {
        su = UV + (size_t)(b * 16 + (rr - 8)) * 512;
        sv = UV + (size_t)(b * 16 + 8 + ch) * 512 + 256;
      }
    }
  }
  const int mtb = (w & 1) * 6;   // mt base (6 tiles)
  const int q = w >> 1;          // nt quarter
  f32x4 acc[6][4] = {};
  for (int half = 0; half < 2; ++half) {
    const int kbase = half * 128;
    if (t < 384) {
      if (su) {
        for (int c = sc0; c < sc0 + 64; c += 4) {
          const f32x4 uu = *(const f32x4*)(su + kbase + c);
          const f32x4 vv = *(const f32x4*)(sv + kbase + c);
          const f32x4 bb = *(const f32x4*)(b1 + kbase + c);
          bf16x4 y;
          for (int e = 0; e < 4; ++e) y[e] = (bf16_t)fmaxf(uu[e] + vv[e] + bb[e], 0.0f);
          *(bf16x4*)(&h1[sr][c]) = y;
        }
      } else {
        for (int c = sc0; c < sc0 + 64; c += 4)
          *(bf16x4*)(&h1[sr][c]) = (bf16x4)0.0f;
      }
    }
    __syncthreads();
    for (int ks = 0; ks < 4; ++ks) {
      const int k = ks * 32 + quad * 8;  // within-phase k, <128
      bf16x8 af[6], bf[4];
      for (int mt = 0; mt < 6; ++mt)
        af[mt] = *(const bf16x8*)(&h1[(mtb + mt) * 16 + col][k]);
      for (int nt = 0; nt < 4; ++nt) {
        const int n = q * 64 + nt * 16 + col;
        bf[nt] = *(const bf16x8*)(W2T + (size_t)n * 256 + kbase + k);
      }
      for (int mt = 0; mt < 6; ++mt)
        for (int nt = 0; nt < 4; ++nt)
          acc[mt][nt] = MFMA16(af[mt], bf[nt], acc[mt][nt]);
    }
    __syncthreads();   // MFMAs done; h1 dead after half==1 -> S/Ag may overlay
  }
  // epilogue: tile-column sums of relu(acc + b2) -> S (overlays h1)
  for (int nt = 0; nt < 4; ++nt) {
    const int n = q * 64 + nt * 16 + col;
    const float b2c = b2[n];
    float sctx = 0.0f;
    for (int mt = 0; mt < 6; ++mt) {
      const int gm = mtb + mt;
      float s = 0.0f;
      for (int reg = 0; reg < 4; ++reg) {
        const int row = gm * 16 + quad * 4 + reg;
        if (row < 56 || row >= 64) s += fmaxf(acc[mt][nt][reg] + b2c, 0.0f);
      }
      s += __shfl_xor(s, 16);
      s += __shfl_xor(s, 32);
      if (gm < 4) {
        sctx += s;                       // only waves with mtb==0
      } else if (lane < 16) {
        S[1 + (gm - 4)][n] = s;
      }
    }
    if (mtb == 0 && lane < 16) S[0][n] = sctx;
  }
  __syncthreads();
  // Ag rows 0..7 = bf16 agg for each choice; rows 8..15 zero (M=16 pad)
  {
    const int ch = t >> 6;
    const int n0 = (t & 63) * 4;
    bf16x4 y;
    for (int e = 0; e < 4; ++e)
      y[e] = (bf16_t)((S[0][n0 + e] + S[1 + ch][n0 + e]) * (1.0f / 72.0f));
    *(bf16x4*)(&Ag[ch][n0]) = y;
    *(bf16x4*)(&Ag[8 + ch][n0]) = (bf16x4)0.0f;
  }
  __syncthreads();
  // f_phi: g = relu(Ag@W3+b3); score = g@W4 + b4. wave w -> n in [w*32,+32).
  f32x4 acc2[2] = {};
  for (int ks = 0; ks < 8; ++ks) {
    const int k = ks * 32 + quad * 8;
    const bf16x8 af = *(const bf16x8*)(&Ag[col][k]);
    for (int nt = 0; nt < 2; ++nt) {
      const int n = w * 32 + nt * 16 + col;
      const bf16x8 bf = *(const bf16x8*)(W3T + (size_t)n * 256 + k);
      acc2[nt] = MFMA16(af, bf, acc2[nt]);
    }
  }
  for (int reg = 0; reg < 4; ++reg) {
    float pr = 0.0f;
    for (int nt = 0; nt < 2; ++nt) {
      const int n = w * 32 + nt * 16 + col;
      pr += fmaxf(acc2[nt][reg] + b3[n], 0.0f) * W4[n];
    }
    pr += __shfl_xor(pr, 1);
    pr += __shfl_xor(pr, 2);
    pr += __shfl_xor(pr, 4);
    pr += __shfl_xor(pr, 8);
    if (col == 0 && quad < 2) red[w][quad * 4 + reg] = pr;  // rows 8..15 dropped
  }
  __syncthreads();
  if (t < 8) {
    float sc = b4[0];
    for (int ww = 0; ww < 8; ++ww) sc += red[ww][t];
    out[b * 8 + t] = sc;
  }
}

extern "C" void kernel_launch(void* const* d_in, const int* in_sizes, int n_in,
                              void* d_out, int out_size, void* d_ws, size_t ws_size,
                              hipStream_t stream) {
  (void)in_sizes; (void)n_in; (void)out_size; (void)ws_size;
  const float* ctx = (const float*)d_in[0];
  const float* cho = (const float*)d_in[1];
  const float* W1  = (const float*)d_in[2];
  const float* b1  = (const float*)d_in[3];
  const float* W2  = (const float*)d_in[4];
  const float* b2  = (const float*)d_in[5];
  const float* W3  = (const float*)d_in[6];
  const float* b3  = (const float*)d_in[7];
  const float* W4  = (const float*)d_in[8];
  const float* b4  = (const float*)d_in[9];
  char* ws = (char*)d_ws;
  bf16_t* Wp   = (bf16_t*)(ws + 0);
  bf16_t* W2T  = (bf16_t*)(ws + 524288);
  bf16_t* W3T  = (bf16_t*)(ws + 655360);
  float*  UV   = (float*)(ws + 786432);
  float*  out  = (float*)d_out;

  prep_kernel<<<dim3(1536), dim3(256), 0, stream>>>(W1, W2, W3, Wp, W2T, W3T);
  k1_kernel<<<dim3(512), dim3(256), 0, stream>>>(ctx, cho, Wp, UV);
  k2_kernel<<<dim3(256), dim3(512), 0, stream>>>(UV, b1, b2, W2T, W3T, b3, W4, b4, out);
}

// Round 6
// 112.416 us; speedup vs baseline: 1.3676x; 1.0288x over previous
//
#include <hip/hip_runtime.h>
#include <hip/hip_bf16.h>

// RelationNetwork fused pipeline, bf16 MFMA (gfx950).
//
// Factorizations:
//  (1) pair@W1 = u[i]+v[j]  -> one 4096x512x512 GEMM (K1).
//  (2) ctx-ctx pair sum is choice-invariant -> computed once per b inside K2.
//  (3) f_phi fused into K2 (agg rows live in LDS; no K3, no aggb round-trip).
//  (4) K1 stages fp32 X into a shared LDS bf16 A-tile (4 waves reuse).
//  (5) r6: UV stored bf16 -- halves UV write + K2 staging traffic; K2's 16 KB
//      per-block working set now fits L1 across its ~12x pair reuse.
//
// ws layout (bytes):
//   [0,        524288)   Wp   bf16 [512][512]  Wp[j][k]=W1'[k][j]
//   [524288,   655360)   W2T  bf16 [256][256]
//   [655360,   786432)   W3T  bf16 [256][256]
//   [786432,   4980736)  UV   bf16 [4096][512] row b*16+p; cols 0..255=u, 256..511=v

typedef __bf16 bf16_t;
typedef bf16_t bf16x8 __attribute__((ext_vector_type(8)));
typedef bf16_t bf16x4 __attribute__((ext_vector_type(4)));
typedef float f32x4 __attribute__((ext_vector_type(4)));

#define MFMA16(a, b, c) __builtin_amdgcn_mfma_f32_16x16x32_bf16((a), (b), (c), 0, 0, 0)

// ---- K0: weight transposes + bf16 conversion (1536 blocks) -----------------
__global__ __launch_bounds__(256) void prep_kernel(
    const float* __restrict__ W1, const float* __restrict__ W2,
    const float* __restrict__ W3, bf16_t* __restrict__ Wp,
    bf16_t* __restrict__ W2T, bf16_t* __restrict__ W3T) {
  const int idx = blockIdx.x * 256 + threadIdx.x;  // 0..393215
  if (idx < 262144) {                      // Wp[j][k], j<256: u-part, else v-part
    const int j = idx >> 9, k = idx & 511;
    const float v = (j < 256) ? W1[k * 256 + j] : W1[(512 + k) * 256 + (j - 256)];
    Wp[idx] = (bf16_t)v;
  } else if (idx < 327680) {               // W2T[n][k] = W2[k][n]
    const int s = idx - 262144;
    const int n = s >> 8, k = s & 255;
    W2T[s] = (bf16_t)W2[k * 256 + n];
  } else {                                 // W3T[n][k] = W3[k][n]
    const int s = idx - 327680;
    const int n = s >> 8, k = s & 255;
    W3T[s] = (bf16_t)W3[k * 256 + n];
  }
}

// ---- K1: UV = X @ Wp^T  (M=4096, N=512, K=512), bf16 output ----------------
// 512 blocks = 64 Mtiles(64) x 8 Ntiles(64); 2 blocks/CU.
// A-tile staged fp32->bf16 into LDS once per block (shared by all 4 waves),
// two K=256 halves. Staging: 4 threads/row, 16B-interleaved columns.
__global__ __launch_bounds__(256) void k1_kernel(
    const float* __restrict__ ctx, const float* __restrict__ cho,
    const bf16_t* __restrict__ Wp, bf16_t* __restrict__ UV) {
  __shared__ bf16_t As[64][264];           // 33.8 KB; row bank-stride 4 -> 2-way max
  const int bm = blockIdx.x & 63;
  const int bn = blockIdx.x >> 6;          // 0..7
  const int t = threadIdx.x;
  const int lane = t & 63;
  const int w = t >> 6;
  const int col = lane & 15;
  const int quad = lane >> 4;
  const int n = bn * 64 + w * 16 + col;
  // staging role: row sr, column base cb (16B-interleaved)
  const int sr = t >> 2;                   // 0..63
  const int gr = bm * 64 + sr;             // X row = b*16 + p
  const int bi = gr >> 4;
  const int p = gr & 15;
  const float* src = (p < 8) ? ctx + (size_t)(bi * 8 + p) * 512
                             : cho + (size_t)(bi * 8 + (p - 8)) * 512;
  const int cb = (t & 3) * 4;
  f32x4 acc[4] = {};
  for (int half = 0; half < 2; ++half) {
    const int kbase = half * 256;
    for (int i = 0; i < 16; ++i) {
      const int c = cb + i * 16;
      const f32x4 x = *(const f32x4*)(src + kbase + c);
      bf16x4 y;
      for (int e = 0; e < 4; ++e) y[e] = (bf16_t)x[e];
      *(bf16x4*)(&As[sr][c]) = y;
    }
    __syncthreads();
    for (int ks = 0; ks < 8; ++ks) {
      const int k = ks * 32 + quad * 8;
      bf16x8 af[4];
      for (int mt = 0; mt < 4; ++mt)
        af[mt] = *(const bf16x8*)(&As[mt * 16 + col][k]);
      const bf16x8 bf = *(const bf16x8*)(Wp + (size_t)n * 512 + kbase + k);
      for (int mt = 0; mt < 4; ++mt) acc[mt] = MFMA16(af[mt], bf, acc[mt]);
    }
    __syncthreads();
  }
  for (int mt = 0; mt < 4; ++mt)
    for (int reg = 0; reg < 4; ++reg) {
      const int r = bm * 64 + mt * 16 + quad * 4 + reg;
      UV[(size_t)r * 512 + n] = (bf16_t)acc[mt][reg];
    }
}

// ---- K2: merged relation stage + f_phi. One block per b (256 blk, 512 thr).
// Rows r in [0,192): r<56 ctx pair; 56..63 zero pad; r=64+ch*16+rr choice pair.
// h1 staged in LDS in two K=128 phases (52 KB). 8 waves: w&1 -> mt half (6),
// w>>1 -> nt quarter. Then (LDS overlay, h1 dead): S[9][256] column sums ->
// Ag[16][264] bf16 agg rows -> f_phi MFMA vs W3T -> W4 dot -> out[b*8+ch].
__global__ __launch_bounds__(512) void k2_kernel(
    const bf16_t* __restrict__ UV, const float* __restrict__ b1,
    const float* __restrict__ b2, const bf16_t* __restrict__ W2T,
    const bf16_t* __restrict__ W3T, const float* __restrict__ b3,
    const float* __restrict__ W4, const float* __restrict__ b4,
    float* __restrict__ out) {
  __shared__ char smem[52224];                      // h1[192][136] bf16
  bf16_t (*h1)[136] = (bf16_t(*)[136])smem;
  float (*S)[256] = (float(*)[256])smem;            // 9216 B (after h1 dead)
  bf16_t (*Ag)[264] = (bf16_t(*)[264])(smem + 9216);   // 8448 B
  float (*red)[8] = (float(*)[8])(smem + 9216 + 8448); // 256 B
  const int b = blockIdx.x;
  const int t = threadIdx.x;
  const int lane = t & 63;
  const int w = t >> 6;
  const int col = lane & 15;
  const int quad = lane >> 4;
  // staging role (threads 0..383: 2 per row)
  const bf16_t* su = nullptr;
  const bf16_t* sv = nullptr;
  int sr = 0, sc0 = 0;
  if (t < 384) {
    sr = t >> 1;
    sc0 = (t & 1) * 64;
    if (sr < 56) {
      const int i = sr / 7;
      const int jj = sr - i * 7;
      const int j = jj + (jj >= i ? 1 : 0);
      su = UV + (size_t)(b * 16 + i) * 512;
      sv = UV + (size_t)(b * 16 + j) * 512 + 256;
    } else if (sr >= 64) {
      const int ch = (sr - 64) >> 4;
      const int rr = (sr - 64) & 15;
      if (rr < 8) {
        su = UV + (size_t)(b * 16 + 8 + ch) * 512;
        sv = UV + (size_t)(b * 16 + rr) * 512 + 256;
      } else {
        su = UV + (size_t)(b * 16 + (rr - 8)) * 512;
        sv = UV + (size_t)(b * 16 + 8 + ch) * 512 + 256;
      }
    }
  }
  const int mtb = (w & 1) * 6;   // mt base (6 tiles)
  const int q = w >> 1;          // nt quarter
  f32x4 acc[6][4] = {};
  for (int half = 0; half < 2; ++half) {
    const int kbase = half * 128;
    if (t < 384) {
      if (su) {
        for (int c = sc0; c < sc0 + 64; c += 8) {
          const bf16x8 u8 = *(const bf16x8*)(su + kbase + c);
          const bf16x8 v8 = *(const bf16x8*)(sv + kbase + c);
          const f32x4 bb0 = *(const f32x4*)(b1 + kbase + c);
          const f32x4 bb1 = *(const f32x4*)(b1 + kbase + c + 4);
          bf16x8 y;
          for (int e = 0; e < 4; ++e)
            y[e] = (bf16_t)fmaxf((float)u8[e] + (float)v8[e] + bb0[e], 0.0f);
          for (int e = 0; e < 4; ++e)
            y[4 + e] = (bf16_t)fmaxf((float)u8[4 + e] + (float)v8[4 + e] + bb1[e], 0.0f);
          *(bf16x8*)(&h1[sr][c]) = y;
        }
      } else {
        for (int c = sc0; c < sc0 + 64; c += 8)
          *(bf16x8*)(&h1[sr][c]) = (bf16x8)0.0f;
      }
    }
    __syncthreads();
    for (int ks = 0; ks < 4; ++ks) {
      const int k = ks * 32 + quad * 8;  // within-phase k, <128
      bf16x8 af[6], bf[4];
      for (int mt = 0; mt < 6; ++mt)
        af[mt] = *(const bf16x8*)(&h1[(mtb + mt) * 16 + col][k]);
      for (int nt = 0; nt < 4; ++nt) {
        const int n = q * 64 + nt * 16 + col;
        bf[nt] = *(const bf16x8*)(W2T + (size_t)n * 256 + kbase + k);
      }
      for (int mt = 0; mt < 6; ++mt)
        for (int nt = 0; nt < 4; ++nt)
          acc[mt][nt] = MFMA16(af[mt], bf[nt], acc[mt][nt]);
    }
    __syncthreads();   // MFMAs done; h1 dead after half==1 -> S/Ag may overlay
  }
  // epilogue: tile-column sums of relu(acc + b2) -> S (overlays h1)
  for (int nt = 0; nt < 4; ++nt) {
    const int n = q * 64 + nt * 16 + col;
    const float b2c = b2[n];
    float sctx = 0.0f;
    for (int mt = 0; mt < 6; ++mt) {
      const int gm = mtb + mt;
      float s = 0.0f;
      for (int reg = 0; reg < 4; ++reg) {
        const int row = gm * 16 + quad * 4 + reg;
        if (row < 56 || row >= 64) s += fmaxf(acc[mt][nt][reg] + b2c, 0.0f);
      }
      s += __shfl_xor(s, 16);
      s += __shfl_xor(s, 32);
      if (gm < 4) {
        sctx += s;                       // only waves with mtb==0
      } else if (lane < 16) {
        S[1 + (gm - 4)][n] = s;
      }
    }
    if (mtb == 0 && lane < 16) S[0][n] = sctx;
  }
  __syncthreads();
  // Ag rows 0..7 = bf16 agg for each choice; rows 8..15 zero (M=16 pad)
  {
    const int ch = t >> 6;
    const int n0 = (t & 63) * 4;
    bf16x4 y;
    for (int e = 0; e < 4; ++e)
      y[e] = (bf16_t)((S[0][n0 + e] + S[1 + ch][n0 + e]) * (1.0f / 72.0f));
    *(bf16x4*)(&Ag[ch][n0]) = y;
    *(bf16x4*)(&Ag[8 + ch][n0]) = (bf16x4)0.0f;
  }
  __syncthreads();
  // f_phi: g = relu(Ag@W3+b3); score = g@W4 + b4. wave w -> n in [w*32,+32).
  f32x4 acc2[2] = {};
  for (int ks = 0; ks < 8; ++ks) {
    const int k = ks * 32 + quad * 8;
    const bf16x8 af = *(const bf16x8*)(&Ag[col][k]);
    for (int nt = 0; nt < 2; ++nt) {
      const int n = w * 32 + nt * 16 + col;
      const bf16x8 bf = *(const bf16x8*)(W3T + (size_t)n * 256 + k);
      acc2[nt] = MFMA16(af, bf, acc2[nt]);
    }
  }
  for (int reg = 0; reg < 4; ++reg) {
    float pr = 0.0f;
    for (int nt = 0; nt < 2; ++nt) {
      const int n = w * 32 + nt * 16 + col;
      pr += fmaxf(acc2[nt][reg] + b3[n], 0.0f) * W4[n];
    }
    pr += __shfl_xor(pr, 1);
    pr += __shfl_xor(pr, 2);
    pr += __shfl_xor(pr, 4);
    pr += __shfl_xor(pr, 8);
    if (col == 0 && quad < 2) red[w][quad * 4 + reg] = pr;  // rows 8..15 dropped
  }
  __syncthreads();
  if (t < 8) {
    float sc = b4[0];
    for (int ww = 0; ww < 8; ++ww) sc += red[ww][t];
    out[b * 8 + t] = sc;
  }
}

extern "C" void kernel_launch(void* const* d_in, const int* in_sizes, int n_in,
                              void* d_out, int out_size, void* d_ws, size_t ws_size,
                              hipStream_t stream) {
  (void)in_sizes; (void)n_in; (void)out_size; (void)ws_size;
  const float* ctx = (const float*)d_in[0];
  const float* cho = (const float*)d_in[1];
  const float* W1  = (const float*)d_in[2];
  const float* b1  = (const float*)d_in[3];
  const float* W2  = (const float*)d_in[4];
  const float* b2  = (const float*)d_in[5];
  const float* W3  = (const float*)d_in[6];
  const float* b3  = (const float*)d_in[7];
  const float* W4  = (const float*)d_in[8];
  const float* b4  = (const float*)d_in[9];
  char* ws = (char*)d_ws;
  bf16_t* Wp   = (bf16_t*)(ws + 0);
  bf16_t* W2T  = (bf16_t*)(ws + 524288);
  bf16_t* W3T  = (bf16_t*)(ws + 655360);
  bf16_t* UV   = (bf16_t*)(ws + 786432);
  float*  out  = (float*)d_out;

  prep_kernel<<<dim3(1536), dim3(256), 0, stream>>>(W1, W2, W3, Wp, W2T, W3T);
  k1_kernel<<<dim3(512), dim3(256), 0, stream>>>(ctx, cho, Wp, UV);
  k2_kernel<<<dim3(256), dim3(512), 0, stream>>>(UV, b1, b2, W2T, W3T, b3, W4, b4, out);
}

// Round 8
// 108.990 us; speedup vs baseline: 1.4106x; 1.0314x over previous
//
#include <hip/hip_runtime.h>
#include <hip/hip_bf16.h>

// RelationNetwork fused pipeline, bf16 MFMA (gfx950).
//
// Factorizations:
//  (1) pair@W1 = u[i]+v[j]  -> one 4096x512x512 GEMM (K1).
//  (2) ctx-ctx pair sum is choice-invariant -> computed once per b inside K2.
//  (3) f_phi fused into K2 (agg rows live in LDS; no K3, no aggb round-trip).
//  (4) K1 stages fp32 X into a shared LDS bf16 A-tile.
//  (5) UV stored bf16 (halves UV write + K2 staging traffic).
//  (6) prep via LDS 64x64 tile transpose (coalesced both sides);
//      K1 256 blocks x 512 thr (A-tile re-read 8x -> 4x, same waves/CU).
//      (r8 fix: prep row loops are 16 iters x 4 rows, not 4 x 4 -- r7 left
//       75% of the transposed weights unwritten.)
//
// ws layout (bytes):
//   [0,        524288)   Wp   bf16 [512][512]  Wp[j][k]=W1'[k][j]
//   [524288,   655360)   W2T  bf16 [256][256]
//   [655360,   786432)   W3T  bf16 [256][256]
//   [786432,   4980736)  UV   bf16 [4096][512] row b*16+p; cols 0..255=u, 256..511=v

typedef __bf16 bf16_t;
typedef bf16_t bf16x8 __attribute__((ext_vector_type(8)));
typedef bf16_t bf16x4 __attribute__((ext_vector_type(4)));
typedef float f32x4 __attribute__((ext_vector_type(4)));

#define MFMA16(a, b, c) __builtin_amdgcn_mfma_f32_16x16x32_bf16((a), (b), (c), 0, 0, 0)

// ---- K0: weight transposes via LDS tiles (96 blocks x 256 thr) -------------
// All sources have leading dim 256. Ts fp32 [64][65]: transpose-read bank
// stride 65%32=1 -> 2-way only. Reads 256 B coalesced, writes 128 B coalesced.
__global__ __launch_bounds__(256) void prep_kernel(
    const float* __restrict__ W1, const float* __restrict__ W2,
    const float* __restrict__ W3, bf16_t* __restrict__ Wp,
    bf16_t* __restrict__ W2T, bf16_t* __restrict__ W3T) {
  __shared__ float Ts[64][65];
  const int b = blockIdx.x;
  const int t = threadIdx.x;
  const int r = t >> 6;          // 0..3
  const int c = t & 63;
  const float* srcP;
  bf16_t* dstP;
  int srcRow, srcCol, dr0, dc0, dstride;
  if (b < 64) {                  // Wp tile: tk = b>>3, tj = b&7
    const int k0 = (b >> 3) * 64, j0 = (b & 7) * 64;
    srcP = W1; dstP = Wp; dstride = 512;
    srcRow = (j0 < 256) ? k0 : 512 + k0;
    srcCol = (j0 < 256) ? j0 : j0 - 256;
    dr0 = j0; dc0 = k0;
  } else if (b < 80) {           // W2T tile
    const int s = b - 64;
    const int k0 = (s >> 2) * 64, n0 = (s & 3) * 64;
    srcP = W2; dstP = W2T; dstride = 256;
    srcRow = k0; srcCol = n0; dr0 = n0; dc0 = k0;
  } else {                       // W3T tile
    const int s = b - 80;
    const int k0 = (s >> 2) * 64, n0 = (s & 3) * 64;
    srcP = W3; dstP = W3T; dstride = 256;
    srcRow = k0; srcCol = n0; dr0 = n0; dc0 = k0;
  }
  for (int i = 0; i < 16; ++i) {           // 16 iters x 4 rows = 64 rows
    const int a = i * 4 + r;
    Ts[a][c] = srcP[(size_t)(srcRow + a) * 256 + srcCol + c];
  }
  __syncthreads();
  for (int i = 0; i < 16; ++i) {
    const int j = i * 4 + r;
    dstP[(size_t)(dr0 + j) * dstride + dc0 + c] = (bf16_t)Ts[c][j];
  }
}

// ---- K1: UV = X @ Wp^T  (M=4096, N=512, K=512), bf16 output ----------------
// 256 blocks = 64 Mtiles(64) x 4 Ntiles(128); 512 thr = 8 waves (4mt x 1nt).
// A-tile staged fp32->bf16 into LDS once per block (8 waves share), two K=256
// halves; staging 8 threads/row, 16B chunks, fully coalesced 128 B groups.
__global__ __launch_bounds__(512) void k1_kernel(
    const float* __restrict__ ctx, const float* __restrict__ cho,
    const bf16_t* __restrict__ Wp, bf16_t* __restrict__ UV) {
  __shared__ bf16_t As[64][264];           // 33.8 KB; row bank-stride 4 -> 2-way max
  const int bm = blockIdx.x & 63;
  const int bn = blockIdx.x >> 6;          // 0..3
  const int t = threadIdx.x;
  const int lane = t & 63;
  const int w = t >> 6;                    // 0..7
  const int col = lane & 15;
  const int quad = lane >> 4;
  const int n = bn * 128 + w * 16 + col;
  // staging role: row sr (8 threads/row), column base cb
  const int sr = t >> 3;                   // 0..63
  const int gr = bm * 64 + sr;             // X row = b*16 + p
  const int bi = gr >> 4;
  const int p = gr & 15;
  const float* src = (p < 8) ? ctx + (size_t)(bi * 8 + p) * 512
                             : cho + (size_t)(bi * 8 + (p - 8)) * 512;
  const int cb = (t & 7) * 4;
  f32x4 acc[4] = {};
  for (int half = 0; half < 2; ++half) {
    const int kbase = half * 256;
    for (int i = 0; i < 8; ++i) {
      const int c = cb + i * 32;
      const f32x4 x = *(const f32x4*)(src + kbase + c);
      bf16x4 y;
      for (int e = 0; e < 4; ++e) y[e] = (bf16_t)x[e];
      *(bf16x4*)(&As[sr][c]) = y;
    }
    __syncthreads();
    for (int ks = 0; ks < 8; ++ks) {
      const int k = ks * 32 + quad * 8;
      bf16x8 af[4];
      for (int mt = 0; mt < 4; ++mt)
        af[mt] = *(const bf16x8*)(&As[mt * 16 + col][k]);
      const bf16x8 bf = *(const bf16x8*)(Wp + (size_t)n * 512 + kbase + k);
      for (int mt = 0; mt < 4; ++mt) acc[mt] = MFMA16(af[mt], bf, acc[mt]);
    }
    __syncthreads();
  }
  for (int mt = 0; mt < 4; ++mt)
    for (int reg = 0; reg < 4; ++reg) {
      const int r = bm * 64 + mt * 16 + quad * 4 + reg;
      UV[(size_t)r * 512 + n] = (bf16_t)acc[mt][reg];
    }
}

// ---- K2: merged relation stage + f_phi. One block per b (256 blk, 512 thr).
// Rows r in [0,192): r<56 ctx pair; 56..63 zero pad; r=64+ch*16+rr choice pair.
// h1 staged in LDS in two K=128 phases (52 KB). 8 waves: w&1 -> mt half (6),
// w>>1 -> nt quarter. Then (LDS overlay, h1 dead): S[9][256] column sums ->
// Ag[16][264] bf16 agg rows -> f_phi MFMA vs W3T -> W4 dot -> out[b*8+ch].
__global__ __launch_bounds__(512) void k2_kernel(
    const bf16_t* __restrict__ UV, const float* __restrict__ b1,
    const float* __restrict__ b2, const bf16_t* __restrict__ W2T,
    const bf16_t* __restrict__ W3T, const float* __restrict__ b3,
    const float* __restrict__ W4, const float* __restrict__ b4,
    float* __restrict__ out) {
  __shared__ char smem[52224];                      // h1[192][136] bf16
  bf16_t (*h1)[136] = (bf16_t(*)[136])smem;
  float (*S)[256] = (float(*)[256])smem;            // 9216 B (after h1 dead)
  bf16_t (*Ag)[264] = (bf16_t(*)[264])(smem + 9216);   // 8448 B
  float (*red)[8] = (float(*)[8])(smem + 9216 + 8448); // 256 B
  const int b = blockIdx.x;
  const int t = threadIdx.x;
  const int lane = t & 63;
  const int w = t >> 6;
  const int col = lane & 15;
  const int quad = lane >> 4;
  // staging role (threads 0..383: 2 per row)
  const bf16_t* su = nullptr;
  const bf16_t* sv = nullptr;
  int sr = 0, sc0 = 0;
  if (t < 384) {
    sr = t >> 1;
    sc0 = (t & 1) * 64;
    if (sr < 56) {
      const int i = sr / 7;
      const int jj = sr - i * 7;
      const int j = jj + (jj >= i ? 1 : 0);
      su = UV + (size_t)(b * 16 + i) * 512;
      sv = UV + (size_t)(b * 16 + j) * 512 + 256;
    } else if (sr >= 64) {
      const int ch = (sr - 64) >> 4;
      const int rr = (sr - 64) & 15;
      if (rr < 8) {
        su = UV + (size_t)(b * 16 + 8 + ch) * 512;
        sv = UV + (size_t)(b * 16 + rr) * 512 + 256;
      } else {
        su = UV + (size_t)(b * 16 + (rr - 8)) * 512;
        sv = UV + (size_t)(b * 16 + 8 + ch) * 512 + 256;
      }
    }
  }
  const int mtb = (w & 1) * 6;   // mt base (6 tiles)
  const int q = w >> 1;          // nt quarter
  f32x4 acc[6][4] = {};
  for (int half = 0; half < 2; ++half) {
    const int kbase = half * 128;
    if (t < 384) {
      if (su) {
        for (int c = sc0; c < sc0 + 64; c += 8) {
          const bf16x8 u8 = *(const bf16x8*)(su + kbase + c);
          const bf16x8 v8 = *(const bf16x8*)(sv + kbase + c);
          const f32x4 bb0 = *(const f32x4*)(b1 + kbase + c);
          const f32x4 bb1 = *(const f32x4*)(b1 + kbase + c + 4);
          bf16x8 y;
          for (int e = 0; e < 4; ++e)
            y[e] = (bf16_t)fmaxf((float)u8[e] + (float)v8[e] + bb0[e], 0.0f);
          for (int e = 0; e < 4; ++e)
            y[4 + e] = (bf16_t)fmaxf((float)u8[4 + e] + (float)v8[4 + e] + bb1[e], 0.0f);
          *(bf16x8*)(&h1[sr][c]) = y;
        }
      } else if (half == 0) {    // zero-pad rows 56..63 once; nothing overwrites
        for (int c = sc0; c < sc0 + 64; c += 8)
          *(bf16x8*)(&h1[sr][c]) = (bf16x8)0.0f;
      }
    }
    __syncthreads();
    for (int ks = 0; ks < 4; ++ks) {
      const int k = ks * 32 + quad * 8;  // within-phase k, <128
      bf16x8 af[6], bf[4];
      for (int mt = 0; mt < 6; ++mt)
        af[mt] = *(const bf16x8*)(&h1[(mtb + mt) * 16 + col][k]);
      for (int nt = 0; nt < 4; ++nt) {
        const int n = q * 64 + nt * 16 + col;
        bf[nt] = *(const bf16x8*)(W2T + (size_t)n * 256 + kbase + k);
      }
      for (int mt = 0; mt < 6; ++mt)
        for (int nt = 0; nt < 4; ++nt)
          acc[mt][nt] = MFMA16(af[mt], bf[nt], acc[mt][nt]);
    }
    __syncthreads();   // MFMAs done; h1 dead after half==1 -> S/Ag may overlay
  }
  // epilogue: tile-column sums of relu(acc + b2) -> S (overlays h1)
  for (int nt = 0; nt < 4; ++nt) {
    const int n = q * 64 + nt * 16 + col;
    const float b2c = b2[n];
    float sctx = 0.0f;
    for (int mt = 0; mt < 6; ++mt) {
      const int gm = mtb + mt;
      float s = 0.0f;
      for (int reg = 0; reg < 4; ++reg) {
        const int row = gm * 16 + quad * 4 + reg;
        if (row < 56 || row >= 64) s += fmaxf(acc[mt][nt][reg] + b2c, 0.0f);
      }
      s += __shfl_xor(s, 16);
      s += __shfl_xor(s, 32);
      if (gm < 4) {
        sctx += s;                       // only waves with mtb==0
      } else if (lane < 16) {
        S[1 + (gm - 4)][n] = s;
      }
    }
    if (mtb == 0 && lane < 16) S[0][n] = sctx;
  }
  __syncthreads();
  // Ag rows 0..7 = bf16 agg for each choice; rows 8..15 zero (M=16 pad)
  {
    const int ch = t >> 6;
    const int n0 = (t & 63) * 4;
    bf16x4 y;
    for (int e = 0; e < 4; ++e)
      y[e] = (bf16_t)((S[0][n0 + e] + S[1 + ch][n0 + e]) * (1.0f / 72.0f));
    *(bf16x4*)(&Ag[ch][n0]) = y;
    *(bf16x4*)(&Ag[8 + ch][n0]) = (bf16x4)0.0f;
  }
  __syncthreads();
  // f_phi: g = relu(Ag@W3+b3); score = g@W4 + b4. wave w -> n in [w*32,+32).
  f32x4 acc2[2] = {};
  for (int ks = 0; ks < 8; ++ks) {
    const int k = ks * 32 + quad * 8;
    const bf16x8 af = *(const bf16x8*)(&Ag[col][k]);
    for (int nt = 0; nt < 2; ++nt) {
      const int n = w * 32 + nt * 16 + col;
      const bf16x8 bf = *(const bf16x8*)(W3T + (size_t)n * 256 + k);
      acc2[nt] = MFMA16(af, bf, acc2[nt]);
    }
  }
  for (int reg = 0; reg < 4; ++reg) {
    float pr = 0.0f;
    for (int nt = 0; nt < 2; ++nt) {
      const int n = w * 32 + nt * 16 + col;
      pr += fmaxf(acc2[nt][reg] + b3[n], 0.0f) * W4[n];
    }
    pr += __shfl_xor(pr, 1);
    pr += __shfl_xor(pr, 2);
    pr += __shfl_xor(pr, 4);
    pr += __shfl_xor(pr, 8);
    if (col == 0 && quad < 2) red[w][quad * 4 + reg] = pr;  // rows 8..15 dropped
  }
  __syncthreads();
  if (t < 8) {
    float sc = b4[0];
    for (int ww = 0; ww < 8; ++ww) sc += red[ww][t];
    out[b * 8 + t] = sc;
  }
}

extern "C" void kernel_launch(void* const* d_in, const int* in_sizes, int n_in,
                              void* d_out, int out_size, void* d_ws, size_t ws_size,
                              hipStream_t stream) {
  (void)in_sizes; (void)n_in; (void)out_size; (void)ws_size;
  const float* ctx = (const float*)d_in[0];
  const float* cho = (const float*)d_in[1];
  const float* W1  = (const float*)d_in[2];
  const float* b1  = (const float*)d_in[3];
  const float* W2  = (const float*)d_in[4];
  const float* b2  = (const float*)d_in[5];
  const float* W3  = (const float*)d_in[6];
  const float* b3  = (const float*)d_in[7];
  const float* W4  = (const float*)d_in[8];
  const float* b4  = (const float*)d_in[9];
  char* ws = (char*)d_ws;
  bf16_t* Wp   = (bf16_t*)(ws + 0);
  bf16_t* W2T  = (bf16_t*)(ws + 524288);
  bf16_t* W3T  = (bf16_t*)(ws + 655360);
  bf16_t* UV   = (bf16_t*)(ws + 786432);
  float*  out  = (float*)d_out;

  prep_kernel<<<dim3(96), dim3(256), 0, stream>>>(W1, W2, W3, Wp, W2T, W3T);
  k1_kernel<<<dim3(256), dim3(512), 0, stream>>>(ctx, cho, Wp, UV);
  k2_kernel<<<dim3(256), dim3(512), 0, stream>>>(UV, b1, b2, W2T, W3T, b3, W4, b4, out);
}